// Round 8
// baseline (269.832 us; speedup 1.0000x reference)
//
#include <hip/hip_runtime.h>
#include <hip/hip_bf16.h>
#include <math.h>

#define S_LEN 4096
#define EMB   1024
#define E3    3072
#define NH    16
#define HD    64

typedef unsigned short u16;
typedef short          bfrag __attribute__((ext_vector_type(8)));  // 8 bf16
typedef float          ffrag __attribute__((ext_vector_type(4)));  // 4 f32
typedef unsigned short us8   __attribute__((ext_vector_type(8)));
typedef unsigned short us4   __attribute__((ext_vector_type(4)));

__device__ __forceinline__ u16 f2bf(float f) {
    union { float f; unsigned u; } v; v.f = f;
    unsigned r = v.u + 0x7fffu + ((v.u >> 16) & 1u);
    return (u16)(r >> 16);
}
// pack two f32 -> two bf16 (truncation) in one v_perm_b32
__device__ __forceinline__ unsigned pack_bf16_trunc(float lo, float hi) {
    union { float f; unsigned u; } a, b; a.f = lo; b.f = hi;
    return __builtin_amdgcn_perm(b.u, a.u, 0x07060302u);
}
// async global->LDS, 16B per lane; LDS dest = uniform base + lane*16
__device__ __forceinline__ void gld16(const void* g, void* l) {
    __builtin_amdgcn_global_load_lds(
        (const __attribute__((address_space(1))) unsigned int*)g,
        (__attribute__((address_space(3))) unsigned int*)l, 16, 0, 0);
}

// ---------------------------------------------------------------------------
// cast fp32 -> bf16, 8 elems/thread
// ---------------------------------------------------------------------------
__global__ __launch_bounds__(256)
void cast_bf16_kernel(const float* __restrict__ in, u16* __restrict__ out) {
    const size_t i = ((size_t)blockIdx.x * 256 + threadIdx.x) * 8;
    float4 a = *(const float4*)(in + i);
    float4 b = *(const float4*)(in + i + 4);
    us8 o;
    o[0]=f2bf(a.x); o[1]=f2bf(a.y); o[2]=f2bf(a.z); o[3]=f2bf(a.w);
    o[4]=f2bf(b.x); o[5]=f2bf(b.y); o[6]=f2bf(b.z); o[7]=f2bf(b.w);
    *(us8*)(out + i) = o;
}

// ---------------------------------------------------------------------------
// transpose+cast: in [R][C] fp32 -> out [C][R] bf16.  64x64 tiles.
// ---------------------------------------------------------------------------
__global__ __launch_bounds__(256)
void transpose_cast_kernel(const float* __restrict__ in, u16* __restrict__ out,
                           int R, int C) {
    __shared__ u16 T[64][72];
    const int r0 = blockIdx.x * 64, c0 = blockIdx.y * 64;
    const int t = threadIdx.x;
    const int rr = t >> 2, cc = (t & 3) * 16;

    const float* ip = in + (size_t)(r0 + rr) * C + c0 + cc;
    u16 tmp[16];
    #pragma unroll
    for (int i4 = 0; i4 < 4; i4++) {
        float4 v = ((const float4*)ip)[i4];
        tmp[4*i4+0]=f2bf(v.x); tmp[4*i4+1]=f2bf(v.y);
        tmp[4*i4+2]=f2bf(v.z); tmp[4*i4+3]=f2bf(v.w);
    }
    #pragma unroll
    for (int i8 = 0; i8 < 2; i8++) {
        us8 vv;
        #pragma unroll
        for (int j = 0; j < 8; j++) vv[j] = tmp[8*i8+j];
        *(us8*)&T[rr][cc + 8*i8] = vv;
    }
    __syncthreads();

    const int oc = t >> 2, orr = (t & 3) * 16;
    u16 ot[16];
    #pragma unroll
    for (int j = 0; j < 16; j++) ot[j] = T[orr + j][oc];
    u16* op = out + (size_t)(c0 + oc) * R + r0 + orr;
    #pragma unroll
    for (int i8 = 0; i8 < 2; i8++) {
        us8 vv;
        #pragma unroll
        for (int j = 0; j < 8; j++) vv[j] = ot[8*i8+j];
        *(us8*)(op + 8*i8) = vv;
    }
}

// ---------------------------------------------------------------------------
// bf16 MFMA GEMM, double-buffered: C[M,N] = A[M,K] * Bt[N,K]^T + bias
// Tile 128 x (32*NT); 4 waves as 2m x 2n; wave does 4x NT 16x16x32 tiles.
// ROPE=1 (requires NT=4):
//   n0 <  2048 : fuse RoPE rotation (+0.125*log2e scale for q) -> Cv (qkvb)
//   n0 >= 2048 : V region -- write bias-added values TRANSPOSED to vtp[d][s]
//                (d = n-2048, contiguous us4 along s); qkvb V region unused.
// ---------------------------------------------------------------------------
template <int OUT_BF16, int NT, int ROPE, int MINW>
__global__ __launch_bounds__(256, MINW)
void gemm_bt_kernel(const u16* __restrict__ A, const u16* __restrict__ Bt,
                    const float* __restrict__ bias, void* __restrict__ Cv,
                    u16* __restrict__ vtp, int M, int N, int K) {
    constexpr int BN = 32 * NT;       // block n-span
    constexpr int WS = 16 * NT;       // wave n-span
    __shared__ u16 As[2][128][32];
    __shared__ u16 Bs[2][BN][32];

    const int tid = threadIdx.x;
    const int w = tid >> 6, L = tid & 63;
    const int col = L & 15, quad = L >> 4;
    const int wm = w & 1, wn = w >> 1;
    const int m0 = blockIdx.x * 128, n0 = blockIdx.y * BN;

    ffrag acc[4][NT];
    #pragma unroll
    for (int a = 0; a < 4; a++)
        #pragma unroll
        for (int b = 0; b < NT; b++)
            #pragma unroll
            for (int r = 0; r < 4; r++) acc[a][b][r] = 0.f;

    const int srow = L >> 2;
    const int schk = L & 3;

    // prologue: stage k=0 into buf 0
    #pragma unroll
    for (int t = 0; t < 2; t++) {
        const int rg = (2 * w + t) * 16;
        gld16(A + (size_t)(m0 + rg + srow) * K + schk * 8, &As[0][rg][0]);
    }
    #pragma unroll
    for (int t = 0; t < NT / 2; t++) {
        const int rg = (w * (NT / 2) + t) * 16;
        gld16(Bt + (size_t)(n0 + rg + srow) * K + schk * 8, &Bs[0][rg][0]);
    }
    __syncthreads();

    int buf = 0;
    for (int k0 = 0; k0 < K; k0 += 32, buf ^= 1) {
        if (k0 + 32 < K) {
            #pragma unroll
            for (int t = 0; t < 2; t++) {
                const int rg = (2 * w + t) * 16;
                gld16(A + (size_t)(m0 + rg + srow) * K + k0 + 32 + schk * 8,
                      &As[buf ^ 1][rg][0]);
            }
            #pragma unroll
            for (int t = 0; t < NT / 2; t++) {
                const int rg = (w * (NT / 2) + t) * 16;
                gld16(Bt + (size_t)(n0 + rg + srow) * K + k0 + 32 + schk * 8,
                      &Bs[buf ^ 1][rg][0]);
            }
        }

        bfrag af[4], bf[NT];
        #pragma unroll
        for (int mt = 0; mt < 4; mt++)
            af[mt] = *(const bfrag*)&As[buf][64 * wm + 16 * mt + col][8 * quad];
        #pragma unroll
        for (int nt = 0; nt < NT; nt++)
            bf[nt] = *(const bfrag*)&Bs[buf][WS * wn + 16 * nt + col][8 * quad];
        #pragma unroll
        for (int mt = 0; mt < 4; mt++)
            #pragma unroll
            for (int nt = 0; nt < NT; nt++)
                acc[mt][nt] = __builtin_amdgcn_mfma_f32_16x16x32_bf16(
                    af[mt], bf[nt], acc[mt][nt], 0, 0, 0);

        __syncthreads();
    }

    float bv[NT];
    #pragma unroll
    for (int nt = 0; nt < NT; nt++) bv[nt] = bias[n0 + WS * wn + 16 * nt + col];

    if (ROPE && n0 < 2 * EMB) {
        // q (n<1024) or k (1024..2047): rotate (d, d+32) pairs.
        const float SCq = (n0 < EMB) ? 0.125f * 1.44269504088896f : 1.0f;
        const float C = 13.287712379549449f / 32.0f;   // log2(10000)/32
        float invf[2];
        invf[0] = exp2f(-(float)col * C);
        invf[1] = exp2f(-(float)(col + 16) * C);
        #pragma unroll
        for (int mt = 0; mt < 4; mt++) {
            #pragma unroll
            for (int r = 0; r < 4; r++) {
                const int mrow = m0 + 64 * wm + 16 * mt + 4 * quad + r;
                const float fs = (float)mrow;
                u16* cp = (u16*)Cv + (size_t)mrow * N + n0 + 64 * wn + col;
                #pragma unroll
                for (int pr = 0; pr < 2; pr++) {
                    float sn, cs;
                    sincosf(fs * invf[pr], &sn, &cs);
                    const float t1 = acc[mt][pr][r] + bv[pr];
                    const float t2 = acc[mt][pr + 2][r] + bv[pr + 2];
                    cp[16 * pr]      = f2bf((t1 * cs - t2 * sn) * SCq);
                    cp[16 * pr + 32] = f2bf((t2 * cs + t1 * sn) * SCq);
                }
            }
        }
    } else if (ROPE) {
        // V region: write transposed to vtp[d][s], d = n - 2048.
        #pragma unroll
        for (int nt = 0; nt < NT; nt++) {
            const int dg = n0 - 2 * EMB + WS * wn + 16 * nt + col;
            #pragma unroll
            for (int mt = 0; mt < 4; mt++) {
                const int s0 = m0 + 64 * wm + 16 * mt + 4 * quad;
                us4 pk;
                #pragma unroll
                for (int r = 0; r < 4; r++) pk[r] = f2bf(acc[mt][nt][r] + bv[nt]);
                *(us4*)&vtp[(size_t)dg * S_LEN + s0] = pk;
            }
        }
    } else {
        #pragma unroll
        for (int mt = 0; mt < 4; mt++) {
            #pragma unroll
            for (int r = 0; r < 4; r++) {
                const int m = m0 + 64 * wm + 16 * mt + 4 * quad + r;
                #pragma unroll
                for (int nt = 0; nt < NT; nt++) {
                    const int n = n0 + WS * wn + 16 * nt + col;
                    const float val = acc[mt][nt][r] + bv[nt];
                    if (OUT_BF16) ((u16*)Cv)[(size_t)m * N + n] = f2bf(val);
                    else          ((float*)Cv)[(size_t)m * N + n] = val;
                }
            }
        }
    }
}

// ---------------------------------------------------------------------------
// flash7: 64-q blocks of 2 waves x 32 q; 1024 blocks, 40 KB LDS ->
// 4 blocks/CU ALL resident, 4 independent barrier phases per CU so one
// block's exp2/VALU overlaps another's MFMA (MFMA blocks its own wave).
// S^T = K Q^T; O^T = V^T P^T; no-shift exp2 softmax; l via ones-MFMA;
// double-buffered K/V via global_load_lds; mask only the last tile.
// 4-round balanced qi schedule: rounds give qi {2a, 63-2a, 2a+1, 62-2a}
// -> per-CU tile sum is constant (130).  id%8 = XCD, 2 heads per XCD.
// ---------------------------------------------------------------------------
__global__ __launch_bounds__(128, 2)
void flash7_kernel(const u16* __restrict__ qkvb, const u16* __restrict__ vt,
                   u16* __restrict__ ctxb) {
    __shared__ u16 QP[2][32][64];     // per-wave: Q rows, then P overlay
    __shared__ u16 Ks[2][64][64];
    __shared__ u16 Vs[2][64][64];

    const int id = blockIdx.x;                    // 0..1023
    const int h  = (id & 7) | (((id >> 3) & 1) << 3);
    const int a  = (id >> 4) & 15;
    const int b  = id >> 8;                       // round 0..3
    int qi;
    if      (b == 0) qi = 2 * a;
    else if (b == 1) qi = 63 - 2 * a;
    else if (b == 2) qi = 2 * a + 1;
    else             qi = 62 - 2 * a;
    const int q0 = qi * 64;
    const int ntk = qi + 1;

    const int tid = threadIdx.x;
    const int w = tid >> 6, L = tid & 63;
    const int col = L & 15, quad = L >> 4;
    const int lr = L >> 3, lp = L & 7;
    const int lc = lp ^ lr;                       // swizzled chunk for staging

    // wave w stages K/V rows 32w..32w+31 (4 gld each) and its own Q rows
    const size_t kArow = (size_t)(32 * w + lr) * E3 + EMB + h * HD + lc * 8;
    const size_t vArow = ((size_t)h * HD + 32 * w + lr) * S_LEN + lc * 8;

    #pragma unroll
    for (int u = 0; u < 4; u++) {
        gld16(qkvb + (size_t)(q0 + 32 * w + 8 * u + lr) * E3 + h * HD + lc * 8,
              &QP[w][8 * u][0]);
        gld16(qkvb + kArow + (size_t)(8 * u) * E3, &Ks[0][32 * w + 8 * u][0]);
        gld16(vt + vArow + (size_t)(8 * u) * S_LEN, &Vs[0][32 * w + 8 * u][0]);
    }
    __syncthreads();

    bfrag qf[2][2];
    #pragma unroll
    for (int i = 0; i < 2; i++)
        #pragma unroll
        for (int ks = 0; ks < 2; ks++)
            qf[i][ks] = *(const bfrag*)
                ((const char*)&QP[w][16 * i + col][0] +
                 16 * ((4 * ks + quad) ^ (col & 7)));

    bfrag ones;
    #pragma unroll
    for (int i = 0; i < 8; i++) ones[i] = (short)0x3F80;

    ffrag o[4][2], ol[2];
    #pragma unroll
    for (int d4 = 0; d4 < 4; d4++)
        #pragma unroll
        for (int i = 0; i < 2; i++)
            #pragma unroll
            for (int r = 0; r < 4; r++) o[d4][i][r] = 0.f;
    #pragma unroll
    for (int i = 0; i < 2; i++)
        #pragma unroll
        for (int r = 0; r < 4; r++) ol[i][r] = 0.f;

    #pragma unroll 1
    for (int t = 0; t < ntk; t++) {
        const int buf = t & 1;
        // prefetch next k-tile into the other buffer (before compute)
        if (t + 1 < ntk) {
            const size_t ko = kArow + (size_t)(t + 1) * 64 * E3;
            const size_t vo = vArow + (size_t)(t + 1) * 64;
            #pragma unroll
            for (int u = 0; u < 4; u++) {
                gld16(qkvb + ko + (size_t)(8 * u) * E3,
                      &Ks[buf ^ 1][32 * w + 8 * u][0]);
                gld16(vt + vo + (size_t)(8 * u) * S_LEN,
                      &Vs[buf ^ 1][32 * w + 8 * u][0]);
            }
        }

        // ---- S^T = K Q^T ----
        ffrag st[4][2];
        #pragma unroll
        for (int t4 = 0; t4 < 4; t4++)
            #pragma unroll
            for (int i = 0; i < 2; i++)
                #pragma unroll
                for (int r = 0; r < 4; r++) st[t4][i][r] = 0.f;
        #pragma unroll
        for (int ks = 0; ks < 2; ks++) {
            bfrag kf[4];
            #pragma unroll
            for (int t4 = 0; t4 < 4; t4++)
                kf[t4] = *(const bfrag*)
                    &Ks[buf][16 * t4 + col][(((4 * ks + quad) ^ (col & 7)) * 8)];
            #pragma unroll
            for (int t4 = 0; t4 < 4; t4++)
                #pragma unroll
                for (int i = 0; i < 2; i++)
                    st[t4][i] = __builtin_amdgcn_mfma_f32_16x16x32_bf16(
                        kf[t4], qf[i][ks], st[t4][i], 0, 0, 0);
        }

        // ---- causal mask: only the last tile ----
        if (t == ntk - 1) {
            #pragma unroll
            for (int i = 0; i < 2; i++) {
                const int qrel = 32 * w + 16 * i + col;
                #pragma unroll
                for (int t4 = 0; t4 < 4; t4++) {
                    const int key0 = 16 * t4 + 4 * quad;
                    #pragma unroll
                    for (int r = 0; r < 4; r++)
                        if (key0 + r > qrel) st[t4][i][r] = -3.0e38f;
                }
            }
        }

        // ---- softmax numerator: p = exp2(s), no shift ----
        #pragma unroll
        for (int i = 0; i < 2; i++) {
            const int prow = 16 * i + col;
            #pragma unroll
            for (int t4 = 0; t4 < 4; t4++) {
                float pr[4];
                #pragma unroll
                for (int r = 0; r < 4; r++) pr[r] = exp2f(st[t4][i][r]);
                uint2 pk;
                pk.x = pack_bf16_trunc(pr[0], pr[1]);
                pk.y = pack_bf16_trunc(pr[2], pr[3]);
                const int c2 = (2 * t4 + (quad >> 1)) ^ (col & 7);
                *(uint2*)((char*)&QP[w][prow][0] + 16 * c2 + 8 * (quad & 1)) = pk;
            }
        }

        // ---- O^T += V^T P^T ;  l += 1^T P^T ----
        #pragma unroll
        for (int ks = 0; ks < 2; ks++) {
            bfrag vf[4];
            #pragma unroll
            for (int d4 = 0; d4 < 4; d4++)
                vf[d4] = *(const bfrag*)
                    &Vs[buf][16 * d4 + col][(((4 * ks + quad) ^ (col & 7)) * 8)];
            bfrag pf[2];
            #pragma unroll
            for (int i = 0; i < 2; i++)
                pf[i] = *(const bfrag*)
                    ((const char*)&QP[w][16 * i + col][0] +
                     16 * ((4 * ks + quad) ^ (col & 7)));
            #pragma unroll
            for (int d4 = 0; d4 < 4; d4++)
                #pragma unroll
                for (int i = 0; i < 2; i++)
                    o[d4][i] = __builtin_amdgcn_mfma_f32_16x16x32_bf16(
                        vf[d4], pf[i], o[d4][i], 0, 0, 0);
            #pragma unroll
            for (int i = 0; i < 2; i++)
                ol[i] = __builtin_amdgcn_mfma_f32_16x16x32_bf16(
                    ones, pf[i], ol[i], 0, 0, 0);
        }

        __syncthreads();   // compute done; next tile's loads drained here
    }

    // ---- epilogue ----
    #pragma unroll
    for (int i = 0; i < 2; i++) {
        const float inv = 1.0f / ol[i][0];
        const int qg = q0 + 32 * w + 16 * i + col;
        #pragma unroll
        for (int d4 = 0; d4 < 4; d4++) {
            us4 pk;
            #pragma unroll
            for (int r = 0; r < 4; r++) pk[r] = f2bf(o[d4][i][r] * inv);
            *(us4*)&ctxb[(size_t)qg * EMB + h * HD + 16 * d4 + 4 * quad] = pk;
        }
    }
}

// ---------------------------------------------------------------------------
extern "C" void kernel_launch(void* const* d_in, const int* in_sizes, int n_in,
                              void* d_out, int out_size, void* d_ws, size_t ws_size,
                              hipStream_t stream) {
    const float* x      = (const float*)d_in[0];
    const float* wqkv_w = (const float*)d_in[2];
    const float* wqkv_b = (const float*)d_in[3];
    const float* out_w  = (const float*)d_in[4];
    const float* out_b  = (const float*)d_in[5];
    float* out = (float*)d_out;

    u16* qkvb = (u16*)d_ws;                        // [4096][3072] (V unused)
    u16* ctxb = qkvb + (size_t)S_LEN * E3;         // [4096][1024]
    u16* xb   = ctxb + (size_t)S_LEN * EMB;        // [4096][1024]
    u16* wt   = xb   + (size_t)S_LEN * EMB;        // [3072][1024]
    u16* owt  = wt   + (size_t)E3 * EMB;           // [1024][1024]
    u16* vtb  = owt  + (size_t)EMB * EMB;          // [16][64][4096]

    dim3 blk(256);

    cast_bf16_kernel<<<dim3(S_LEN * EMB / (256 * 8)), blk, 0, stream>>>(x, xb);
    transpose_cast_kernel<<<dim3(EMB / 64, E3 / 64), blk, 0, stream>>>(
        wqkv_w, wt, EMB, E3);
    transpose_cast_kernel<<<dim3(EMB / 64, EMB / 64), blk, 0, stream>>>(
        out_w, owt, EMB, EMB);

    // QKV projection + fused RoPE (+ q pre-scale) + fused V transpose
    gemm_bt_kernel<1, 4, 1, 3><<<dim3(S_LEN / 128, E3 / 128), blk, 0, stream>>>(
        xb, wt, wqkv_b, qkvb, vtb, S_LEN, E3, EMB);

    flash7_kernel<<<dim3(1024), dim3(128), 0, stream>>>(qkvb, vtb, ctxb);

    // output projection, 128x64 tiles -> 512 blocks (2/CU)
    gemm_bt_kernel<0, 2, 0, 2><<<dim3(S_LEN / 128, EMB / 64), blk, 0, stream>>>(
        ctxb, owt, out_b, out, nullptr, S_LEN, EMB, EMB);
}